// Round 6
// baseline (130.572 us; speedup 1.0000x reference)
//
#include <hip/hip_runtime.h>
#include <hip/hip_bf16.h>

#define N 8192
#define FIN 512
#define FOUT 64
#define L2E 1.44269504089f
#define SPLIT 8
#define MSTRIDE 34  // mask row stride in dwords (padded, even for u64 writes)

typedef __attribute__((address_space(1))) const void* gas_cptr;
typedef __attribute__((address_space(3))) void* las_ptr;
typedef float f32x4 __attribute__((ext_vector_type(4)));
typedef short bf16x8 __attribute__((ext_vector_type(8)));

#if __has_builtin(__builtin_amdgcn_exp2f)
#define EXP2(x) __builtin_amdgcn_exp2f(x)
#else
#define EXP2(x) exp2f(x)
#endif

static __device__ __forceinline__ unsigned short f2bf_rne(float f) {
  unsigned u = __float_as_uint(f);
  u += 0x7FFFu + ((u >> 16) & 1u);
  return (unsigned short)(u >> 16);
}
static __device__ __forceinline__ unsigned fkey(float f) {
  unsigned u = __float_as_uint(f);
  return (u & 0x80000000u) ? ~u : (u | 0x80000000u);
}

// ---- K1: WhT(bf16) = (h @ W)^T via bf16 MFMA; src2/dst2 = (Wh@a)*log2e ----
__global__ __launch_bounds__(256) void k_wh(
    const float* __restrict__ h, const float* __restrict__ W,
    const float* __restrict__ a, unsigned short* __restrict__ WhT,
    float* __restrict__ src2, float* __restrict__ dst2,
    unsigned* __restrict__ dmaxk) {
  __shared__ __attribute__((aligned(16))) char wts[64 * 512 * 2];   // [f][k] swz
  __shared__ __attribute__((aligned(16))) char hsb[2][64 * 64 * 2]; // [row][k] swz

  const int t = threadIdx.x;
  const int w = t >> 6;
  const int ll = t & 63;
  const int lc = ll & 15;
  const int row0 = blockIdx.x * 64;

  {
    const int k0 = t * 2;
#pragma unroll
    for (int f4 = 0; f4 < 16; ++f4) {
      float4 x0 = *reinterpret_cast<const float4*>(&W[(size_t)k0 * FOUT + f4 * 4]);
      float4 x1 = *reinterpret_cast<const float4*>(&W[(size_t)(k0 + 1) * FOUT + f4 * 4]);
      const float e0[4] = {x0.x, x0.y, x0.z, x0.w};
      const float e1[4] = {x1.x, x1.y, x1.z, x1.w};
#pragma unroll
      for (int e = 0; e < 4; ++e) {
        int f = f4 * 4 + e;
        int bb = f * 1024 + k0 * 2;
        bb ^= (f & 7) << 4;
        *reinterpret_cast<ushort2*>(wts + bb) =
            make_ushort2(f2bf_rne(e0[e]), f2bf_rne(e1[e]));
      }
    }
  }
  __syncthreads();

  f32x4 acc[4];
#pragma unroll
  for (int c = 0; c < 4; ++c) acc[c] = (f32x4){0.f, 0.f, 0.f, 0.f};

  const int hrow = 16 * w + (ll >> 2);
  const float* hbase = &h[(size_t)(row0 + hrow) * FIN + (ll & 3) * 16];

#define LOADH(dst, kc)                                                        \
  do {                                                                        \
    dst[0] = *reinterpret_cast<const float4*>(hbase + (kc));                  \
    dst[1] = *reinterpret_cast<const float4*>(hbase + (kc) + 4);              \
    dst[2] = *reinterpret_cast<const float4*>(hbase + (kc) + 8);              \
    dst[3] = *reinterpret_cast<const float4*>(hbase + (kc) + 12);             \
  } while (0)

#define WRITEH(buf, src)                                                      \
  do {                                                                        \
    int bb0 = hrow * 128 + (ll & 3) * 32;                                     \
    bb0 ^= (hrow & 7) << 4;                                                   \
    _Pragma("unroll") for (int q = 0; q < 4; ++q) {                           \
      ushort4 u = make_ushort4(f2bf_rne(src[q].x), f2bf_rne(src[q].y),        \
                               f2bf_rne(src[q].z), f2bf_rne(src[q].w));       \
      *reinterpret_cast<ushort4*>(hsb[buf] + (bb0 ^ (q * 8))) = u;            \
    }                                                                         \
  } while (0)

#define MFMA_CHUNK(buf, kcb)                                                  \
  do {                                                                        \
    _Pragma("unroll") for (int k0 = 0; k0 < 2; ++k0) {                        \
      int arow = 16 * w + lc;                                                 \
      int ab = arow * 128 + k0 * 64 + ((ll >> 4) << 4);                       \
      ab ^= (arow & 7) << 4;                                                  \
      bf16x8 af = *reinterpret_cast<const bf16x8*>(hsb[buf] + ab);            \
      _Pragma("unroll") for (int c = 0; c < 4; ++c) {                         \
        int f = c * 16 + lc;                                                  \
        int bb = f * 1024 + (kcb) + k0 * 64 + ((ll >> 4) << 4);               \
        bb ^= (f & 7) << 4;                                                   \
        bf16x8 bfr = *reinterpret_cast<const bf16x8*>(wts + bb);              \
        acc[c] = __builtin_amdgcn_mfma_f32_16x16x32_bf16(af, bfr, acc[c], 0, 0, 0); \
      }                                                                       \
    }                                                                         \
  } while (0)

  float4 ha[4], hb[4];
  LOADH(ha, 0);
#pragma unroll
  for (int c2 = 0; c2 < 4; ++c2) {
    WRITEH(0, ha);
    LOADH(hb, (2 * c2 + 1) * 64);
    MFMA_CHUNK(0, (2 * c2) * 128);
    WRITEH(1, hb);
    if (c2 < 3) LOADH(ha, (2 * c2 + 2) * 64);
    MFMA_CHUNK(1, (2 * c2 + 1) * 128);
  }

  float a1v[4], a2v[4];
#pragma unroll
  for (int c = 0; c < 4; ++c) {
    a1v[c] = a[c * 16 + lc];
    a2v[c] = a[FOUT + c * 16 + lc];
  }
  float p1[4], p2[4];
#pragma unroll
  for (int q = 0; q < 4; ++q) {
    p1[q] = acc[0][q] * a1v[0] + acc[1][q] * a1v[1] + acc[2][q] * a1v[2] + acc[3][q] * a1v[3];
    p2[q] = acc[0][q] * a2v[0] + acc[1][q] * a2v[1] + acc[2][q] * a2v[2] + acc[3][q] * a2v[3];
  }
#pragma unroll
  for (int msk = 8; msk >= 1; msk >>= 1)
#pragma unroll
    for (int q = 0; q < 4; ++q) {
      p1[q] += __shfl_xor(p1[q], msk);
      p2[q] += __shfl_xor(p2[q], msk);
    }
#pragma unroll
  for (int q = 0; q < 4; ++q) { p1[q] *= L2E; p2[q] *= L2E; }

  const int r0 = row0 + 16 * w + ((ll >> 4) << 2);
  if (lc == 0) {
#pragma unroll
    for (int q = 0; q < 4; ++q) { src2[r0 + q] = p1[q]; dst2[r0 + q] = p2[q]; }
  }
#pragma unroll
  for (int c = 0; c < 4; ++c) {
    ushort4 u = make_ushort4(f2bf_rne(acc[c][0]), f2bf_rne(acc[c][1]),
                             f2bf_rne(acc[c][2]), f2bf_rne(acc[c][3]));
    *reinterpret_cast<ushort4*>(&WhT[(size_t)(c * 16 + lc) * N + r0]) = u;
  }
  float wm = fmaxf(fmaxf(p2[0], p2[1]), fmaxf(p2[2], p2[3]));
  wm = fmaxf(wm, __shfl_xor(wm, 16));
  wm = fmaxf(wm, __shfl_xor(wm, 32));
  if (ll == 0) atomicMax(dmaxk, fkey(wm));
#undef LOADH
#undef WRITEH
#undef MFMA_CHUNK
}

// ---- K2: fused adj-stream + masked softmax + bf16 MFMA PV -----------------
// Phase A: each wave streams its own 16 adj rows, ballot-packs to LDS mask.
// ONE __syncthreads between A and B (LDS fence: stops TBAA reordering of the
// ull mask stores vs unsigned loads — the R5 bug). Phase B: 16 sub-tiles,
// softmax from LDS mask, B-fragments direct from L2-resident WhT, P via
// wave-private pbs (write->read same-wave, no barrier needed: R2-R4 proven).
__global__ __launch_bounds__(256) void k_attn(
    const int* __restrict__ adj, const unsigned short* __restrict__ WhT,
    const float* __restrict__ src2, const float* __restrict__ dst2,
    const unsigned* __restrict__ dmaxk, float* __restrict__ out,
    float* __restrict__ Opart, float* __restrict__ lpart, const int split) {
  __shared__ unsigned mskd[64 * MSTRIDE];
  __shared__ __attribute__((aligned(16))) char pbs[8192];  // [i][j] bf16 swz

  const int t = threadIdx.x;
  const int w = t >> 6;
  const int ll = t & 63;
  const int rg = t >> 4;
  const int cg = t & 15;
  const int i0 = rg * 4;
  const int lc = ll & 15;
  const int g16 = (ll >> 4) << 4;
  const int g8 = (ll >> 4) << 3;
  const int row0 = blockIdx.x * 64;
  const int jlen = N / split;
  const int jbase = blockIdx.y * jlen;

  unsigned kk = dmaxk[0];
  const float dmax2 = (kk & 0x80000000u) ? __uint_as_float(kk & 0x7FFFFFFFu)
                                         : __uint_as_float(~kk);

  float s2v[4], m2[4], l[4];
#pragma unroll
  for (int r = 0; r < 4; ++r) {
    s2v[r] = src2[row0 + i0 + r];
    float x = s2v[r] + dmax2;
    m2[r] = fmaxf(x, 0.2f * x);
    l[r] = 0.f;
  }

  f32x4 acc[4];
#pragma unroll
  for (int c = 0; c < 4; ++c) acc[c] = (f32x4){0.f, 0.f, 0.f, 0.f};

  const int bsh = (cg & 7) * 4;

  for (int mt = 0; mt < jlen; mt += 1024) {
    const int mbase = jbase + mt;

    // ---- phase A: stream 16 adj rows (this wave's), pack to LDS ----
#pragma unroll 1
    for (int s = 0; s < 16; ++s) {
      const int row = 16 * w + s;
      const int* ar = adj + (size_t)(row0 + row) * N + mbase;
      unsigned x[16];
#pragma unroll
      for (int k = 0; k < 16; ++k) x[k] = ar[k * 64 + ll];
      unsigned long long b[16];
#pragma unroll
      for (int k = 0; k < 16; ++k) b[k] = __ballot(x[k] != 0);
      if (ll == 0) {
        unsigned long long* mrow =
            reinterpret_cast<unsigned long long*>(&mskd[row * MSTRIDE]);
#pragma unroll
        for (int k = 0; k < 16; ++k) mrow[k] = b[k];
      }
    }
    __syncthreads();  // mask visible; fences compiler reordering (R5 bug fix)

    // ---- phase B: 16 sub-tiles of 64 j ----
    unsigned mw[4], nmw[4];
    float dv[4], ndv[4];
#pragma unroll
    for (int r = 0; r < 4; ++r)
      mw[r] = mskd[(i0 + r) * MSTRIDE + (cg >> 3)];
    {
      float4 d_ = *reinterpret_cast<const float4*>(&dst2[mbase + cg * 4]);
      dv[0] = d_.x; dv[1] = d_.y; dv[2] = d_.z; dv[3] = d_.w;
    }

#pragma unroll 1
    for (int jt2 = 0; jt2 < 16; ++jt2) {
      const int j0 = mbase + jt2 * 64;

      // B-fragments straight from global (L2-resident WhT), issued first
      bf16x8 bfr[2][4];
#pragma unroll
      for (int k0 = 0; k0 < 2; ++k0)
#pragma unroll
        for (int c = 0; c < 4; ++c)
          bfr[k0][c] = *reinterpret_cast<const bf16x8*>(
              &WhT[(size_t)(c * 16 + lc) * N + j0 + k0 * 32 + g8]);

      // prefetch next sub-tile's mask words + dst2
      if (jt2 + 1 < 16) {
#pragma unroll
        for (int r = 0; r < 4; ++r)
          nmw[r] = mskd[(i0 + r) * MSTRIDE + (jt2 + 1) * 2 + (cg >> 3)];
        float4 d_ = *reinterpret_cast<const float4*>(&dst2[j0 + 64 + cg * 4]);
        ndv[0] = d_.x; ndv[1] = d_.y; ndv[2] = d_.z; ndv[3] = d_.w;
      }

      // softmax (log2 domain, fixed bound m2)
      float p[4][4];
#pragma unroll
      for (int r = 0; r < 4; ++r) {
        unsigned b = mw[r] >> bsh;
#pragma unroll
        for (int jj = 0; jj < 4; ++jj) {
          float x = s2v[r] + dv[jj];
          float e2 = fmaxf(x, 0.2f * x);
          float pe = EXP2(e2 - m2[r]);
          pe = (b & (1u << jj)) ? pe : 0.f;
          p[r][jj] = pe;
          l[r] += pe;
        }
      }
      // pack P rows (wave-private) into pbs, swizzled
#pragma unroll
      for (int r = 0; r < 4; ++r) {
        unsigned u0 = __float_as_uint(p[r][0]);
        unsigned u1 = __float_as_uint(p[r][1]);
        unsigned u2 = __float_as_uint(p[r][2]);
        unsigned u3 = __float_as_uint(p[r][3]);
        uint2 pk = make_uint2((u0 >> 16) | (u1 & 0xFFFF0000u),
                              (u2 >> 16) | (u3 & 0xFFFF0000u));
        int row = i0 + r;
        int ba = (row << 7) + (cg << 3);
        ba ^= (row & 7) << 4;
        *reinterpret_cast<uint2*>(pbs + ba) = pk;
      }

      // MFMA PV
#pragma unroll
      for (int k0 = 0; k0 < 2; ++k0) {
        int arow = 16 * w + lc;
        int ab = (arow << 7) + k0 * 64 + g16;
        ab ^= (arow & 7) << 4;
        bf16x8 af = *reinterpret_cast<const bf16x8*>(pbs + ab);
#pragma unroll
        for (int c = 0; c < 4; ++c)
          acc[c] = __builtin_amdgcn_mfma_f32_16x16x32_bf16(af, bfr[k0][c],
                                                           acc[c], 0, 0, 0);
      }

      if (jt2 + 1 < 16) {
#pragma unroll
        for (int r = 0; r < 4; ++r) { mw[r] = nmw[r]; dv[r] = ndv[r]; }
      }
    }

    if (mt + 1024 < jlen) __syncthreads();  // before mskd overwrite (unused at split=8)
  }

  // reduce l over the 16 cg lanes
#pragma unroll
  for (int msk = 8; msk >= 1; msk >>= 1)
#pragma unroll
    for (int r = 0; r < 4; ++r) l[r] += __shfl_xor(l[r], msk);

  const int orow = row0 + 16 * w + ((ll >> 4) << 2);
  const int ocol = ll & 15;
  if (split == 1) {
#pragma unroll
    for (int c = 0; c < 4; ++c)
#pragma unroll
      for (int q = 0; q < 4; ++q)
        out[(size_t)(orow + q) * FOUT + c * 16 + ocol] = acc[c][q] / l[q];
  } else {
    const int pb = blockIdx.y;
#pragma unroll
    for (int c = 0; c < 4; ++c)
#pragma unroll
      for (int q = 0; q < 4; ++q)
        Opart[((size_t)pb * N + orow + q) * FOUT + c * 16 + ocol] = acc[c][q];
    if (cg == 0) {
#pragma unroll
      for (int r = 0; r < 4; ++r)
        lpart[(size_t)pb * N + row0 + i0 + r] = l[r];
    }
  }
}

// ---- K3: combine split partials (shared m => plain sums) ------------------
__global__ __launch_bounds__(256) void k_combine(
    const float* __restrict__ Opart, const float* __restrict__ lpart,
    float* __restrict__ out, const int split) {
  int idx = blockIdx.x * 256 + threadIdx.x;
  int row = idx >> 6;
  float num = 0.f, den = 0.f;
  for (int k = 0; k < split; ++k) {
    num += Opart[(size_t)k * N * FOUT + idx];
    den += lpart[(size_t)k * N + row];
  }
  out[idx] = num / den;
}

// ---- launcher --------------------------------------------------------------
extern "C" void kernel_launch(void* const* d_in, const int* in_sizes, int n_in,
                              void* d_out, int out_size, void* d_ws, size_t ws_size,
                              hipStream_t stream) {
  const float* h = (const float*)d_in[0];
  const int* adj = (const int*)d_in[1];
  const float* W = (const float*)d_in[2];
  const float* a = (const float*)d_in[3];
  float* out = (float*)d_out;

  unsigned short* WhT = (unsigned short*)d_ws;  // 64*N bf16 = 1MB
  float* src2 = (float*)(WhT + (size_t)FOUT * N);
  float* dst2 = src2 + N;
  unsigned* dmaxk = (unsigned*)(dst2 + N);
  float* Opart = (float*)(dmaxk + 64);

  const size_t base_bytes = (size_t)FOUT * N * 2 + 2 * N * 4 + 256;
  int split = SPLIT;
  while (split > 1 &&
         base_bytes + (size_t)split * ((size_t)N * FOUT + N) * 4 > ws_size)
    split >>= 1;
  float* lpart = Opart + (size_t)split * N * FOUT;

  hipMemsetAsync(dmaxk, 0, 4, stream);
  k_wh<<<dim3(N / 64), 256, 0, stream>>>(h, W, a, WhT, src2, dst2, dmaxk);
  k_attn<<<dim3(N / 64, split), 256, 0, stream>>>(adj, WhT, src2, dst2, dmaxk,
                                                  out, Opart, lpart, split);
  if (split > 1)
    k_combine<<<dim3((N * FOUT) / 256), 256, 0, stream>>>(Opart, lpart, out, split);
}